// Round 6
// baseline (3661.831 us; speedup 1.0000x reference)
//
#include <hip/hip_runtime.h>
#include <math.h>

#define Nn 20000
#define Ee 200000
#define Hh 128
#define Ll 10

#define NB_PROJ 313          // (Nn+63)/64 row-blocks for the two projections
#define NB_EDGE (Ee/64)      // 3125
#define NB_AGG  (Nn/4)       // 5000 (Nn divisible by 4)
#define NB_ATTN ((Nn+255)/256) // 79

using short8  = __attribute__((ext_vector_type(8))) short;
using floatx4 = __attribute__((ext_vector_type(4))) float;

__device__ __forceinline__ float bf2f(unsigned short u){ return __uint_as_float(((unsigned)u)<<16); }
__device__ __forceinline__ unsigned short f2bf(float f){
  unsigned u = __float_as_uint(f);
  u += 0x7FFF + ((u>>16)&1);
  return (unsigned short)(u>>16);
}
// sigmoid-form GELU (r2 evidence: cut edge VALU time 82->60us; err ~1e-3 vs erf)
__device__ __forceinline__ float gelu_f(float x){
  float x3 = x*x*x;
  float z = 1.595769122f*x + 0.071354816f*x3;
  return x / (1.0f + __expf(-z));
}

// ---------------------------------------------------------------------------
// MLP body (device fn): 3-segment gather -> L(384,256)+LN+GELU -> L(256,128)
//   +LN -> fp32 residual (+ bf16 mirror). W1 LDS-staged double-buffered
//   (1 barrier/chunk); W2 streamed per-wave from L2 (r6: its 8 barriers cost
//   more than 192KB of L2-hot redundancy; GEMM2 is only 64 MFMAs).
// Occupancy is register-quantum-locked at 2 waves/SIMD (r2/r3: caps <=170
// spill; combined demand ~164 regs rounds to 256-quantum). Latency hiding
// therefore comes from co-dispatched independent blocks (mega_edge).
// ---------------------------------------------------------------------------
template<bool GATHER>
__device__ __forceinline__ void mlp_body(int bid,
               const unsigned short* __restrict__ s0,
               const unsigned short* __restrict__ s1,
               const unsigned short* __restrict__ s2b,
               const float* __restrict__ s2f,
               const int* __restrict__ rowI, const int* __restrict__ colI,
               const unsigned short* __restrict__ w1p,
               const unsigned short* __restrict__ w2p,
               const float* __restrict__ pb1, const float* __restrict__ pg1,
               const float* __restrict__ pbb1,
               const float* __restrict__ pb2, const float* __restrict__ pg2,
               const float* __restrict__ pbb2,
               float* __restrict__ resf,
               unsigned short* __restrict__ resb,
               int M)
{
  __shared__ __align__(16) unsigned short wbuf[2][8192];    // 2 x 16KB W1 chunks
  __shared__ __align__(16) unsigned short lds_h[4][16*264]; // per-wave h tile
  __shared__ float lds_par[1152];

  const int tid = threadIdx.x;
  const int w = tid>>6, lane = tid&63, l16 = lane&15, q = lane>>4;
  const int R0 = bid*64;

  for (int u = tid; u < 1152; u += 256){
    float v;
    if      (u <  256) v = pb1[u];
    else if (u <  512) v = pg1[u-256];
    else if (u <  768) v = pbb1[u-512];
    else if (u <  896) v = pb2[u-768];
    else if (u < 1024) v = pg2[u-896];
    else               v = pbb2[u-1024];
    lds_par[u] = v;
  }

  // ---- prologue: stage W1 chunk 0 ----
  {
    const unsigned short* src = w1p;
    #pragma unroll
    for (int i=0;i<4;++i)
      *(short8*)&wbuf[0][tid*8 + i*2048] = *(const short8*)(src + tid*8 + i*2048);
  }

  const int gA = R0 + w*16 + l16;

  // ---- preload A fragments ----
  short8 af[12];
  if (GATHER){
    const unsigned short* p0 = s0 + (size_t)rowI[gA]*Hh + q*8;
    const unsigned short* p1 = s1 + (size_t)colI[gA]*Hh + q*8;
    const float*          p2 = s2f + (size_t)gA*Hh + q*8;
    #pragma unroll
    for (int c=0;c<4;++c){
      af[c]   = *(const short8*)(p0 + c*32);
      af[4+c] = *(const short8*)(p1 + c*32);
      float4 u0 = *(const float4*)(p2 + c*32);
      float4 u1 = *(const float4*)(p2 + c*32 + 4);
      short8 t8;
      t8[0]=(short)f2bf(u0.x); t8[1]=(short)f2bf(u0.y);
      t8[2]=(short)f2bf(u0.z); t8[3]=(short)f2bf(u0.w);
      t8[4]=(short)f2bf(u1.x); t8[5]=(short)f2bf(u1.y);
      t8[6]=(short)f2bf(u1.z); t8[7]=(short)f2bf(u1.w);
      af[8+c] = t8;
    }
  } else {
    int gg = gA < M ? gA : (M-1);
    const unsigned short* p0 = s0 + (size_t)gg*Hh + q*8;
    const unsigned short* p1 = s1 + (size_t)gg*Hh + q*8;
    const unsigned short* p2 = s2b + (size_t)gg*Hh + q*8;
    #pragma unroll
    for (int c=0;c<4;++c){
      af[c]   = *(const short8*)(p0 + c*32);
      af[4+c] = *(const short8*)(p1 + c*32);
      af[8+c] = *(const short8*)(p2 + c*32);
    }
  }

  __syncthreads();   // lds_par + wbuf[0] ready

  const floatx4 fz = {0.f,0.f,0.f,0.f};
  floatx4 acc1[16];
  #pragma unroll
  for (int t=0;t<16;++t) acc1[t] = fz;

  // ---- GEMM1: 12 chunks, W1 double-buffered, 1 barrier per staged chunk ----
  #pragma unroll
  for (int c=0;c<12;++c){
    const int sel = c&1, nsel = sel^1;
    short8 nx0, nx1, nx2, nx3;
    if (c < 11){
      const unsigned short* src = w1p + (size_t)(c+1)*8192;
      nx0 = *(const short8*)(src + tid*8);
      nx1 = *(const short8*)(src + tid*8 + 2048);
      nx2 = *(const short8*)(src + tid*8 + 4096);
      nx3 = *(const short8*)(src + tid*8 + 6144);
    }
    #pragma unroll
    for (int t=0;t<16;++t){
      short8 bf = *(const short8*)&wbuf[sel][t*512 + lane*8];
      acc1[t] = __builtin_amdgcn_mfma_f32_16x16x32_bf16(af[c], bf, acc1[t], 0,0,0);
    }
    if (c < 11){
      *(short8*)&wbuf[nsel][tid*8]        = nx0;
      *(short8*)&wbuf[nsel][tid*8 + 2048] = nx1;
      *(short8*)&wbuf[nsel][tid*8 + 4096] = nx2;
      *(short8*)&wbuf[nsel][tid*8 + 6144] = nx3;
      __syncthreads();
    }
  }

  // ---- epilogue 1: bias + LN(256) + GELU -> lds_h (per-wave, no barrier) ----
  #pragma unroll
  for (int r=0;r<4;++r){
    float hv[16];
    float s=0.f, ss=0.f;
    #pragma unroll
    for (int t=0;t<16;++t){
      float v = acc1[t][r] + lds_par[t*16+l16];
      hv[t]=v; s+=v; ss+=v*v;
    }
    #pragma unroll
    for (int m=1;m<16;m<<=1){ s += __shfl_xor(s,m); ss += __shfl_xor(ss,m); }
    float mean = s*(1.f/256.f);
    float var  = ss*(1.f/256.f) - mean*mean;
    float rstd = rsqrtf(var + 1e-5f);
    int ro = q*4 + r;
    #pragma unroll
    for (int t=0;t<16;++t){
      int col = t*16+l16;
      float hh = (hv[t]-mean)*rstd*lds_par[256+col] + lds_par[512+col];
      lds_h[w][ro*264 + col] = f2bf(gelu_f(hh));
    }
  }

  floatx4 acc2[8];
  #pragma unroll
  for (int t=0;t<8;++t) acc2[t] = fz;

  // ---- GEMM2: W2 streamed per-wave from L2 (no barriers) ----
  const unsigned short* w2l = w2p + (size_t)lane*8;
  #pragma unroll
  for (int c=0;c<8;++c){
    short8 a2 = *(const short8*)&lds_h[w][l16*264 + c*32 + q*8];
    #pragma unroll
    for (int t=0;t<8;++t){
      short8 bf = *(const short8*)(w2l + (size_t)(c*8+t)*512);
      acc2[t] = __builtin_amdgcn_mfma_f32_16x16x32_bf16(a2, bf, acc2[t], 0,0,0);
    }
  }

  // ---- epilogue 2: bias + LN(128) + residual (+ bf16 mirror) ----
  #pragma unroll
  for (int r=0;r<4;++r){
    float vv[8];
    float s=0.f, ss=0.f;
    #pragma unroll
    for (int t=0;t<8;++t){
      float v = acc2[t][r] + lds_par[768 + t*16+l16];
      vv[t]=v; s+=v; ss+=v*v;
    }
    #pragma unroll
    for (int m=1;m<16;m<<=1){ s += __shfl_xor(s,m); ss += __shfl_xor(ss,m); }
    float mean = s*(1.f/128.f);
    float var  = ss*(1.f/128.f) - mean*mean;
    float rstd = rsqrtf(var + 1e-5f);
    int g = R0 + w*16 + q*4 + r;
    if (g < M){
      #pragma unroll
      for (int t=0;t<8;++t){
        int col = t*16+l16;
        float outv = (vv[t]-mean)*rstd*lds_par[896+col] + lds_par[1024+col];
        size_t idx = (size_t)g*Hh + col;
        float nv = resf[idx] + outv;
        resf[idx] = nv;
        if (!GATHER) resb[idx] = f2bf(nv);
      }
    }
  }
}

// ---------------------------------------------------------------------------
// Projection body (device fn): out[M,NCOLS] = bf16(A @ Wp + bias), K=128.
// ---------------------------------------------------------------------------
template<int NCOLS>
__device__ __forceinline__ void proj_body(int bid,
               const unsigned short* __restrict__ A,
               const unsigned short* __restrict__ Wp,
               const float* __restrict__ bias,
               unsigned short* __restrict__ out,
               int M)
{
  constexpr int NT = NCOLS/16;
  const int tid = threadIdx.x;
  const int w = tid>>6, lane = tid&63, l16 = lane&15, q = lane>>4;
  const int R0 = bid*64;
  int gA = R0 + w*16 + l16;
  int ga = gA < M ? gA : (M-1);
  const unsigned short* ap = A + (size_t)ga*128 + q*8;

  const floatx4 fz = {0.f,0.f,0.f,0.f};
  floatx4 acc[NT];
  #pragma unroll
  for (int t=0;t<NT;++t) acc[t] = fz;

  const unsigned short* wl = Wp + (size_t)lane*8;
  #pragma unroll
  for (int c=0;c<4;++c){
    short8 af = *(const short8*)(ap + c*32);
    #pragma unroll
    for (int t=0;t<NT;++t){
      short8 bf = *(const short8*)(wl + (size_t)(c*NT+t)*512);
      acc[t] = __builtin_amdgcn_mfma_f32_16x16x32_bf16(af, bf, acc[t], 0,0,0);
    }
  }
  #pragma unroll
  for (int r=0;r<4;++r){
    int g = R0 + w*16 + q*4 + r;
    if (g < M){
      #pragma unroll
      for (int t=0;t<NT;++t){
        int col = t*16+l16;
        out[(size_t)g*NCOLS + col] = f2bf(acc[t][r] + bias[col]);
      }
    }
  }
}

// ---------------------------------------------------------------------------
// mega_edge: kv-proj (313) + qn-proj (313) + edge MLP (3125) in ONE dispatch.
// All three read-only on x_b16/out_e inputs, disjoint outputs -> legal merge.
// The 626 small blocks fill latency bubbles of the 2-block/CU edge waves.
// ---------------------------------------------------------------------------
__global__ __launch_bounds__(256, 2)
void mega_edge(const unsigned short* __restrict__ xb,
               const float* __restrict__ ef,
               const int* __restrict__ rowI, const int* __restrict__ colI,
               const unsigned short* __restrict__ w1p,
               const unsigned short* __restrict__ w2p,
               const float* __restrict__ pb1, const float* __restrict__ pg1,
               const float* __restrict__ pbb1,
               const float* __restrict__ pb2, const float* __restrict__ pg2,
               const float* __restrict__ pbb2,
               float* __restrict__ resf,
               const unsigned short* __restrict__ kvp, const float* __restrict__ bkv,
               unsigned short* __restrict__ kvb,
               const unsigned short* __restrict__ qnp, const float* __restrict__ bqn,
               unsigned short* __restrict__ qnb)
{
  int bid = blockIdx.x;
  if (bid < NB_PROJ){
    proj_body<256>(bid, xb, kvp, bkv, kvb, Nn);
    return;
  }
  if (bid < 2*NB_PROJ){
    proj_body<128>(bid - NB_PROJ, xb, qnp, bqn, qnb, Nn);
    return;
  }
  mlp_body<true>(bid - 2*NB_PROJ, xb, xb, nullptr, ef, rowI, colI,
                 w1p, w2p, pb1, pg1, pbb1, pb2, pg2, pbb2,
                 resf, nullptr, Ee);
}

// node MLP (separate dispatch: depends on agg_b/ctx_b)
__global__ __launch_bounds__(256, 2)
void node_mlp(const unsigned short* __restrict__ xb,
              const unsigned short* __restrict__ aggb,
              const unsigned short* __restrict__ ctxb,
              const unsigned short* __restrict__ w1p,
              const unsigned short* __restrict__ w2p,
              const float* __restrict__ pb1, const float* __restrict__ pg1,
              const float* __restrict__ pbb1,
              const float* __restrict__ pb2, const float* __restrict__ pg2,
              const float* __restrict__ pbb2,
              float* __restrict__ resf,
              unsigned short* __restrict__ resb)
{
  mlp_body<false>(blockIdx.x, xb, aggb, ctxb, nullptr, nullptr, nullptr,
                  w1p, w2p, pb1, pg1, pbb1, pb2, pg2, pbb2,
                  resf, resb, Nn);
}

// ---------------------------------------------------------------------------
// mega2: CSR scatter-mean gather (5000 blocks) + token-attn reduce (79).
// attn phase-2 restructured: both tokens share one v-load; j-range split in 2
// across thread groups (serial length 256 -> 128).
// ---------------------------------------------------------------------------
__global__ __launch_bounds__(256, 4)
void mega2(const float* __restrict__ ef, const int* __restrict__ rowPtr,
           const int* __restrict__ elist, const float* __restrict__ invd,
           unsigned short* __restrict__ aggb,
           const unsigned short* __restrict__ kv, const float* __restrict__ tq,
           float* __restrict__ onum, float* __restrict__ denom)
{
  const int bid = blockIdx.x;
  const int tid = threadIdx.x;

  if (bid < NB_AGG){
    int n = bid*4 + (tid>>6);
    int lane = tid&63;
    if (n >= Nn) return;
    int j0 = rowPtr[n], j1 = rowPtr[n+1];
    float s0=0.f,s1=0.f,t0=0.f,t1=0.f,u0=0.f,u1=0.f,v0=0.f,v1=0.f;
    int j = j0;
    for (; j+3 < j1; j += 4){
      int e0=elist[j], e1=elist[j+1], e2=elist[j+2], e3=elist[j+3];
      float2 a = *(const float2*)(ef + (size_t)e0*Hh + lane*2);
      float2 b = *(const float2*)(ef + (size_t)e1*Hh + lane*2);
      float2 c = *(const float2*)(ef + (size_t)e2*Hh + lane*2);
      float2 d = *(const float2*)(ef + (size_t)e3*Hh + lane*2);
      s0+=a.x; s1+=a.y; t0+=b.x; t1+=b.y; u0+=c.x; u1+=c.y; v0+=d.x; v1+=d.y;
    }
    for (; j < j1; ++j){
      int e0 = elist[j];
      float2 a = *(const float2*)(ef + (size_t)e0*Hh + lane*2);
      s0+=a.x; s1+=a.y;
    }
    s0 += t0+u0+v0; s1 += t1+u1+v1;
    float iv = invd[n];
    unsigned int packed = ((unsigned)f2bf(s1*iv) << 16) | (unsigned)f2bf(s0*iv);
    *(unsigned int*)&aggb[(size_t)n*Hh + lane*2] = packed;
    return;
  }

  // ---- token-attention reduce ----
  __shared__ float sbuf[8][256];
  __shared__ float qs[256];
  qs[tid] = tq[tid];
  __syncthreads();
  const int base = (bid - NB_AGG)*256;
  const int i = base + tid;
  float ex[8];
  if (i < Nn){
    const unsigned short* kr = kv + (size_t)i*256;
    float acc[8];
    #pragma unroll
    for (int a=0;a<8;++a) acc[a]=0.f;
    #pragma unroll
    for (int d8=0; d8<16; ++d8){
      short8 k8 = *(const short8*)(kr + d8*8);
      #pragma unroll
      for (int u=0;u<8;++u){
        int d = d8*8+u;
        float kd = bf2f((unsigned short)k8[u]);
        int h = d>>5;
        acc[h]   += qs[d]*kd;
        acc[4+h] += qs[128+d]*kd;
      }
    }
    #pragma unroll
    for (int a=0;a<8;++a) ex[a] = expf(acc[a]*0.17677669529663688f);
  } else {
    #pragma unroll
    for (int a=0;a<8;++a) ex[a]=0.f;
  }
  #pragma unroll
  for (int a=0;a<8;++a) sbuf[a][tid] = ex[a];
  __syncthreads();

  const int jh = tid>>7, h = (tid>>5)&3, d = tid&31;
  int cnt = Nn - base; if (cnt > 256) cnt = 256;
  int j0 = jh*128, j1 = j0+128;
  if (j0 > cnt) j0 = cnt;
  if (j1 > cnt) j1 = cnt;
  float a0=0.f, a1=0.f, w0s=0.f, w1s=0.f;
  for (int j=j0; j<j1; ++j){
    float w0 = sbuf[h][j];
    float w1 = sbuf[4+h][j];
    float vv = bf2f(kv[(size_t)(base+j)*256 + 128 + h*32 + d]);
    a0 += w0*vv; a1 += w1*vv; w0s += w0; w1s += w1;
  }
  atomicAdd(&onum[h*32+d], a0);
  atomicAdd(&onum[128+h*32+d], a1);
  if (d==0){ atomicAdd(&denom[h], w0s); atomicAdd(&denom[4+h], w1s); }
}

// ---------------------------------------------------------------------------
// Token transformer block (2 tokens, fp32) + node-attn k/v projection.
// ---------------------------------------------------------------------------
__global__ void token_kernel(const float* __restrict__ onum, const float* __restrict__ denom,
  const float* __restrict__ tok_wo, const float* __restrict__ tok_bo,
  const float* __restrict__ token_embed,
  const float* __restrict__ g1, const float* __restrict__ b1,
  const float* __restrict__ g2, const float* __restrict__ b2,
  const float* __restrict__ ff_w1, const float* __restrict__ ff_b1,
  const float* __restrict__ ff_w2, const float* __restrict__ ff_b2,
  const float* __restrict__ nod_wqkv, const float* __restrict__ nod_bqkv,
  float* __restrict__ kv2)
{
  __shared__ float O[2][128];
  __shared__ float T[2][128];
  __shared__ float F[2][512];
  __shared__ float stats[4];
  int tid = threadIdx.x;
  int t = tid>>7, c = tid&127;
  {
    int th = t*4 + (c>>5);
    O[t][c] = onum[th*32 + (c&31)] / denom[th];
  }
  __syncthreads();
  {
    float s = tok_bo[c];
    for (int k=0;k<128;++k) s += O[t][k]*tok_wo[k*128+c];
    T[t][c] = token_embed[t*128+c] + s;
  }
  __syncthreads();
  if (tid < 2){
    float s=0.f, ss=0.f;
    for (int k=0;k<128;++k){ float v=T[tid][k]; s+=v; ss+=v*v; }
    float m = s*(1.f/128.f);
    stats[tid*2] = m;
    stats[tid*2+1] = rsqrtf(ss*(1.f/128.f)-m*m+1e-5f);
  }
  __syncthreads();
  T[t][c] = (T[t][c]-stats[t*2])*stats[t*2+1]*g1[c] + b1[c];
  __syncthreads();
  for (int u=0;u<4;++u){
    int o = tid + u*256;
    int tt = o>>9, j = o&511;
    float s = ff_b1[j];
    for (int k=0;k<128;++k) s += T[tt][k]*ff_w1[k*512+j];
    F[tt][j] = gelu_f(s);
  }
  __syncthreads();
  {
    float s = ff_b2[c];
    for (int k=0;k<512;++k) s += F[t][k]*ff_w2[k*128+c];
    O[t][c] = T[t][c] + s;
  }
  __syncthreads();
  if (tid < 2){
    float s=0.f, ss=0.f;
    for (int k=0;k<128;++k){ float v=O[tid][k]; s+=v; ss+=v*v; }
    float m = s*(1.f/128.f);
    stats[tid*2] = m;
    stats[tid*2+1] = rsqrtf(ss*(1.f/128.f)-m*m+1e-5f);
  }
  __syncthreads();
  O[t][c] = (O[t][c]-stats[t*2])*stats[t*2+1]*g2[c] + b2[c];
  __syncthreads();
  for (int u=0;u<2;++u){
    int o = tid + u*256;
    int tt = o>>8, cc = o&255;
    float s = nod_bqkv[128+cc];
    for (int k=0;k<128;++k) s += O[tt][k]*nod_wqkv[k*384+128+cc];
    if (cc < 128) kv2[tt*128+cc] = s;                  // k2
    else          kv2[256 + tt*128 + (cc-128)] = s;    // v2
  }
}

// ---------------------------------------------------------------------------
// attn_wo_gemm: per-node attention over the 2 global tokens computed
// IN-REGISTER as the A-fragment of the wo GEMM (deletes node_attn dispatch
// and the at_b roundtrip). p(i,head c) reduced over q via 2 shfl_xor.
// ---------------------------------------------------------------------------
__global__ __launch_bounds__(256, 4)
void attn_wo_gemm(const unsigned short* __restrict__ qn,
                  const float* __restrict__ kv2,
                  const unsigned short* __restrict__ wop,
                  const float* __restrict__ nod_bo,
                  unsigned short* __restrict__ out,
                  int M)
{
  __shared__ float k2s[256], v2s[256];
  const int tid = threadIdx.x;
  k2s[tid] = kv2[tid];
  v2s[tid] = kv2[256+tid];
  __syncthreads();
  const int w = tid>>6, lane = tid&63, l16 = lane&15, q = lane>>4;
  const int R0 = blockIdx.x*64;
  int gA = R0 + w*16 + l16;
  int ga = gA < M ? gA : (M-1);
  const unsigned short* ap = qn + (size_t)ga*128 + q*8;

  const floatx4 fz = {0.f,0.f,0.f,0.f};
  floatx4 acc[8];
  #pragma unroll
  for (int t=0;t<8;++t) acc[t] = fz;
  const unsigned short* wl = wop + (size_t)lane*8;

  #pragma unroll
  for (int c=0;c<4;++c){
    short8 qv8 = *(const short8*)(ap + c*32);
    float qv[8];
    float p0=0.f, p1=0.f;
    #pragma unroll
    for (int j=0;j<8;++j){
      qv[j] = bf2f((unsigned short)qv8[j]);
      int col = c*32 + q*8 + j;          // head = c for all 8 cols
      p0 += qv[j]*k2s[col];
      p1 += qv[j]*k2s[128+col];
    }
    p0 += __shfl_xor(p0,16); p0 += __shfl_xor(p0,32);  // reduce over q
    p1 += __shfl_xor(p1,16); p1 += __shfl_xor(p1,32);
    float e0 = __expf(p0*0.17677669529663688f);
    float e1 = __expf(p1*0.17677669529663688f);
    float inv = 1.0f/(e0+e1);
    short8 a;
    #pragma unroll
    for (int j=0;j<8;++j){
      int col = c*32 + q*8 + j;
      a[j] = (short)f2bf((e0*v2s[col] + e1*v2s[128+col])*inv);
    }
    #pragma unroll
    for (int t=0;t<8;++t){
      short8 bf = *(const short8*)(wl + (size_t)(c*8+t)*512);
      acc[t] = __builtin_amdgcn_mfma_f32_16x16x32_bf16(a, bf, acc[t], 0,0,0);
    }
  }
  #pragma unroll
  for (int r=0;r<4;++r){
    int g = R0 + w*16 + q*4 + r;
    if (g < M){
      #pragma unroll
      for (int t=0;t<8;++t){
        int col = t*16+l16;
        out[(size_t)g*128 + col] = f2bf(acc[t][r] + nod_bo[col]);
      }
    }
  }
}

// ---------------------------------------------------------------------------
// CSR build (one-time; edge_index constant across layers).
// ---------------------------------------------------------------------------
__global__ void csr_prefix(const int* __restrict__ cnt, int* __restrict__ rowPtr)
{
  __shared__ int part[256];
  const int tid = threadIdx.x;
  const int CH = (Nn + 255)/256;
  int c0 = tid*CH; if (c0 > Nn) c0 = Nn;
  int c1 = c0+CH;  if (c1 > Nn) c1 = Nn;
  int s = 0;
  for (int i=c0;i<c1;++i) s += cnt[i];
  part[tid] = s;
  __syncthreads();
  for (int d=1; d<256; d<<=1){
    int v = (tid>=d) ? part[tid-d] : 0;
    __syncthreads();
    part[tid] += v;
    __syncthreads();
  }
  int off = part[tid] - s;
  for (int i=c0;i<c1;++i){ rowPtr[i] = off; off += cnt[i]; }
  if (tid == 255) rowPtr[Nn] = off;
}

__global__ void csr_fill(const int* __restrict__ colI, const int* __restrict__ rowPtr,
                         int* __restrict__ cursor, int* __restrict__ elist)
{
  int e = blockIdx.x*256 + threadIdx.x;
  if (e < Ee){
    int n = colI[e];
    int p = atomicAdd(&cursor[n], 1);
    elist[rowPtr[n] + p] = e;
  }
}

// ---------------------------------------------------------------------------
// One-time prep: fp32 -> bf16 weight packing into MFMA fragment order.
// ---------------------------------------------------------------------------
__global__ void prep_weights(const float* __restrict__ ew1,
  const float* __restrict__ ew2,
  const float* __restrict__ nw1,
  const float* __restrict__ nw2,
  const float* __restrict__ tok_wqkv,
  const float* __restrict__ nod_wqkv,
  const float* __restrict__ nod_wo,
  const float* __restrict__ token_embed,
  const float* __restrict__ tok_bqkv,
  unsigned short* __restrict__ ew1p, unsigned short* __restrict__ ew2p,
  unsigned short* __restrict__ nw1p, unsigned short* __restrict__ nw2p,
  unsigned short* __restrict__ kvp, unsigned short* __restrict__ qnp,
  unsigned short* __restrict__ wop, float* __restrict__ tq)
{
  int gid = blockIdx.x*256 + threadIdx.x;
  if (gid < Ll*98304){             // W1 pack: [12 chunks][16 tiles][64 lanes][8]
    int l = gid / 98304; int idx = gid % 98304;
    int c = idx >> 13;
    int t = (idx >> 9) & 15;
    int lane = (idx >> 3) & 63;
    int j = idx & 7;
    int k = c*32 + (lane>>4)*8 + j;
    int n = t*16 + (lane&15);
    size_t src = (size_t)l*98304 + (size_t)k*256 + n;
    ew1p[gid] = f2bf(ew1[src]);
    nw1p[gid] = f2bf(nw1[src]);
  }
  if (gid < Ll*32768){             // W2 pack: [8 chunks][8 tiles][64][8]
    int l = gid / 32768; int idx = gid % 32768;
    int c = idx >> 12;
    int t = (idx >> 9) & 7;
    int lane = (idx >> 3) & 63;
    int j = idx & 7;
    int k = c*32 + (lane>>4)*8 + j;
    int n = t*16 + (lane&15);
    size_t src = (size_t)l*32768 + (size_t)k*128 + n;
    ew2p[gid] = f2bf(ew2[src]);
    nw2p[gid] = f2bf(nw2[src]);
  }
  if (gid < 32768){                // kv proj pack: [4 chunks][16 tiles][64][8]
    int c = gid >> 13;
    int t = (gid >> 9) & 15;
    int lane = (gid >> 3) & 63;
    int j = gid & 7;
    int k = c*32 + (lane>>4)*8 + j;
    int n = t*16 + (lane&15);
    kvp[gid] = f2bf(tok_wqkv[(size_t)k*384 + 128 + n]);
  }
  if (gid < 16384){                // q / wo pack: [4 chunks][8 tiles][64][8]
    int c = gid >> 12;
    int t = (gid >> 9) & 7;
    int lane = (gid >> 3) & 63;
    int j = gid & 7;
    int k = c*32 + (lane>>4)*8 + j;
    int n = t*16 + (lane&15);
    qnp[gid] = f2bf(nod_wqkv[(size_t)k*384 + n]);
    wop[gid] = f2bf(nod_wo[(size_t)k*128 + n]);
  }
  if (gid < 256){
    int t = gid >> 7, c = gid & 127;
    float s = tok_bqkv[c];
    for (int k=0;k<128;++k) s += token_embed[t*128+k] * tok_wqkv[k*384+c];
    tq[gid] = s;
  }
}

__global__ void init_state(const float* __restrict__ x_in,
  const float* __restrict__ e_in,
  float* __restrict__ x_f32, float* __restrict__ e_f32,
  unsigned short* __restrict__ x_b16)
{
  size_t gid = (size_t)blockIdx.x*256 + threadIdx.x;
  if (gid < (size_t)Ee*Hh) e_f32[gid] = e_in[gid];
  if (gid < (size_t)Nn*Hh){
    float v = x_in[gid];
    x_f32[gid] = v;
    x_b16[gid] = f2bf(v);
  }
}

__global__ void deg_count(const int* __restrict__ colI, int* __restrict__ cnt){
  int gid = blockIdx.x*256+threadIdx.x;
  if (gid < Ee) atomicAdd(&cnt[colI[gid]], 1);
}
__global__ void deg_inv(const int* __restrict__ cnt, float* __restrict__ inv){
  int gid = blockIdx.x*256+threadIdx.x;
  if (gid < Nn){ int c = cnt[gid]; inv[gid] = 1.0f / (float)(c > 1 ? c : 1); }
}

// ---------------------------------------------------------------------------
extern "C" void kernel_launch(void* const* d_in, const int* in_sizes, int n_in,
                              void* d_out, int out_size, void* d_ws, size_t ws_size,
                              hipStream_t stream)
{
  const float* x_in       = (const float*)d_in[0];
  const int*   eidx       = (const int*)d_in[1];
  const float* e_in       = (const float*)d_in[2];
  const float* edge_w1    = (const float*)d_in[3];
  const float* edge_b1    = (const float*)d_in[4];
  const float* edge_ln1g  = (const float*)d_in[5];
  const float* edge_ln1b  = (const float*)d_in[6];
  const float* edge_w2    = (const float*)d_in[7];
  const float* edge_b2    = (const float*)d_in[8];
  const float* edge_ln2g  = (const float*)d_in[9];
  const float* edge_ln2b  = (const float*)d_in[10];
  const float* node_w1    = (const float*)d_in[11];
  const float* node_b1    = (const float*)d_in[12];
  const float* node_ln1g  = (const float*)d_in[13];
  const float* node_ln1b  = (const float*)d_in[14];
  const float* node_w2    = (const float*)d_in[15];
  const float* node_b2    = (const float*)d_in[16];
  const float* node_ln2g  = (const float*)d_in[17];
  const float* node_ln2b  = (const float*)d_in[18];
  const float* token_embed= (const float*)d_in[19];
  const float* tok_wqkv   = (const float*)d_in[20];
  const float* tok_bqkv   = (const float*)d_in[21];
  const float* tok_wo     = (const float*)d_in[22];
  const float* tok_bo     = (const float*)d_in[23];
  const float* ln_t1g     = (const float*)d_in[24];
  const float* ln_t1b     = (const float*)d_in[25];
  const float* ln_t2g     = (const float*)d_in[26];
  const float* ln_t2b     = (const float*)d_in[27];
  const float* ff_w1      = (const float*)d_in[28];
  const float* ff_b1      = (const float*)d_in[29];
  const float* ff_w2      = (const float*)d_in[30];
  const float* ff_b2      = (const float*)d_in[31];
  const float* nod_wqkv   = (const float*)d_in[32];
  const float* nod_bqkv   = (const float*)d_in[33];
  const float* nod_wo     = (const float*)d_in[34];
  const float* nod_bo     = (const float*)d_in[35];

  const int* rowI = eidx;
  const int* colI = eidx + Ee;

  float* out_x = (float*)d_out;                    // fp32 master of x (output 0)
  float* out_e = out_x + (size_t)Nn*Hh;            // fp32 master of edge_attr (output 1)

  char* base = (char*)d_ws;
  size_t off = 0;
  auto alloc = [&](size_t bytes)->char*{
    char* p = base + off; off += (bytes + 255) & ~(size_t)255; return p;
  };
  unsigned short* x_b16 = (unsigned short*)alloc((size_t)Nn*Hh*2);
  unsigned short* agg_b = (unsigned short*)alloc((size_t)Nn*Hh*2);
  unsigned short* ctx_b = (unsigned short*)alloc((size_t)Nn*Hh*2);
  unsigned short* kv_b  = (unsigned short*)alloc((size_t)Nn*256*2);
  unsigned short* qn_b  = (unsigned short*)alloc((size_t)Nn*Hh*2);
  float*          invd  = (float*)alloc((size_t)Nn*4);
  int*            dcnt  = (int*)alloc((size_t)Nn*4);
  int*            rowP  = (int*)alloc((size_t)(Nn+1)*4);
  int*            curs  = (int*)alloc((size_t)Nn*4);
  int*            elist = (int*)alloc((size_t)Ee*4);
  unsigned short* ew1p  = (unsigned short*)alloc((size_t)Ll*98304*2);
  unsigned short* ew2p  = (unsigned short*)alloc((size_t)Ll*32768*2);
  unsigned short* nw1p  = (unsigned short*)alloc((size_t)Ll*98304*2);
  unsigned short* nw2p  = (unsigned short*)alloc((size_t)Ll*32768*2);
  unsigned short* kvp   = (unsigned short*)alloc((size_t)32768*2);
  unsigned short* qnp   = (unsigned short*)alloc((size_t)16384*2);
  unsigned short* wop   = (unsigned short*)alloc((size_t)16384*2);
  float*          tq    = (float*)alloc(256*4);
  float*          kv2   = (float*)alloc(512*4);
  float*          onum  = (float*)alloc(264*4);
  float*          denom = onum + 256;
  if (off > ws_size) return;  // insufficient workspace: fail loudly (no writes)

  hipMemsetAsync(dcnt, 0, (size_t)Nn*4, stream);
  hipMemsetAsync(curs, 0, (size_t)Nn*4, stream);
  prep_weights<<<(Ll*98304 + 255)/256, 256, 0, stream>>>(
      edge_w1, edge_w2, node_w1, node_w2, tok_wqkv, nod_wqkv, nod_wo,
      token_embed, tok_bqkv, ew1p, ew2p, nw1p, nw2p, kvp, qnp, wop, tq);
  init_state<<<(int)(((size_t)Ee*Hh + 255)/256), 256, 0, stream>>>(
      x_in, e_in, out_x, out_e, x_b16);
  deg_count<<<(Ee+255)/256, 256, 0, stream>>>(colI, dcnt);
  csr_prefix<<<1, 256, 0, stream>>>(dcnt, rowP);
  deg_inv<<<(Nn+255)/256, 256, 0, stream>>>(dcnt, invd);
  csr_fill<<<(Ee+255)/256, 256, 0, stream>>>(colI, rowP, curs, elist);

  for (int l = 0; l < Ll; ++l){
    hipMemsetAsync(onum, 0, 264*4, stream);

    // edge MLP + kv/qn projections (one dispatch; independent inputs)
    mega_edge<<<2*NB_PROJ + NB_EDGE, 256, 0, stream>>>(
        x_b16, out_e, rowI, colI,
        ew1p + (size_t)l*98304, ew2p + (size_t)l*32768,
        edge_b1 + l*256, edge_ln1g + l*256, edge_ln1b + l*256,
        edge_b2 + l*128, edge_ln2g + l*128, edge_ln2b + l*128,
        out_e,
        kvp, tok_bqkv+128, kv_b,
        qnp, nod_bqkv, qn_b);

    // scatter-mean gather + token-attn reduce (one dispatch)
    mega2<<<NB_AGG + NB_ATTN, 256, 0, stream>>>(
        out_e, rowP, elist, invd, agg_b, kv_b, tq, onum, denom);

    token_kernel<<<1, 256, 0, stream>>>(onum, denom, tok_wo, tok_bo, token_embed,
        ln_t1g, ln_t1b, ln_t2g, ln_t2b, ff_w1, ff_b1, ff_w2, ff_b2,
        nod_wqkv, nod_bqkv, kv2);

    // fused per-node attention + wo projection
    attn_wo_gemm<<<NB_PROJ, 256, 0, stream>>>(qn_b, kv2, wop, nod_bo, ctx_b, Nn);

    // node MLP + residual (refreshes x bf16 mirror)
    node_mlp<<<NB_PROJ, 256, 0, stream>>>(x_b16, agg_b, ctx_b,
        nw1p + (size_t)l*98304, nw2p + (size_t)l*32768,
        node_b1 + l*256, node_ln1g + l*256, node_ln1b + l*256,
        node_b2 + l*128, node_ln2g + l*128, node_ln2b + l*128,
        out_x, x_b16);
  }
}

// Round 8
// 3442.935 us; speedup vs baseline: 1.0636x; 1.0636x over previous
//
#include <hip/hip_runtime.h>
#include <math.h>

#define Nn 20000
#define Ee 200000
#define Hh 128
#define Ll 10

#define NB_PROJ 313            // (Nn+63)/64 row-blocks for the projections
#define NB_EDGE (Ee/64)        // 3125
#define NB_AGG  (Nn/4)         // 5000
#define NB_ATTN ((Nn+255)/256) // 79

using short8  = __attribute__((ext_vector_type(8))) short;
using floatx4 = __attribute__((ext_vector_type(4))) float;

__device__ __forceinline__ float bf2f(unsigned short u){ return __uint_as_float(((unsigned)u)<<16); }
__device__ __forceinline__ unsigned short f2bf(float f){
  unsigned u = __float_as_uint(f);
  u += 0x7FFF + ((u>>16)&1);
  return (unsigned short)(u>>16);
}
// sigmoid-form GELU (r2 evidence: cut edge VALU time 82->60us; err ~1e-3 vs erf)
__device__ __forceinline__ float gelu_f(float x){
  float x3 = x*x*x;
  float z = 1.595769122f*x + 0.071354816f*x3;
  return x / (1.0f + __expf(-z));
}

// ---------------------------------------------------------------------------
// MLP body — EXACT r5 structure (best measured: 170us for 3125 blocks).
// W1 AND W2 both LDS-staged, double-buffered (r6 lesson: streaming W2 from L2
// re-introduced the redundant-stream latency wall; cost ~14us/dispatch).
// Occupancy register-quantum-locked at 2 waves/SIMD; latency hiding comes
// from co-dispatched independent blocks (mega_edge tail).
// ---------------------------------------------------------------------------
template<bool GATHER>
__device__ __forceinline__ void mlp_body(int bid,
               const unsigned short* __restrict__ s0,
               const unsigned short* __restrict__ s1,
               const unsigned short* __restrict__ s2b,
               const float* __restrict__ s2f,
               const int* __restrict__ rowI, const int* __restrict__ colI,
               const unsigned short* __restrict__ w1p,
               const unsigned short* __restrict__ w2p,
               const float* __restrict__ pb1, const float* __restrict__ pg1,
               const float* __restrict__ pbb1,
               const float* __restrict__ pb2, const float* __restrict__ pg2,
               const float* __restrict__ pbb2,
               float* __restrict__ resf,
               unsigned short* __restrict__ resb,
               int M)
{
  __shared__ __align__(16) unsigned short wbuf[2][8192];    // 2 x 16KB weight chunks
  __shared__ __align__(16) unsigned short lds_h[4][16*264]; // per-wave h tile
  __shared__ float lds_par[1152];

  const int tid = threadIdx.x;
  const int w = tid>>6, lane = tid&63, l16 = lane&15, q = lane>>4;
  const int R0 = bid*64;

  for (int u = tid; u < 1152; u += 256){
    float v;
    if      (u <  256) v = pb1[u];
    else if (u <  512) v = pg1[u-256];
    else if (u <  768) v = pbb1[u-512];
    else if (u <  896) v = pb2[u-768];
    else if (u < 1024) v = pg2[u-896];
    else               v = pbb2[u-1024];
    lds_par[u] = v;
  }

  // ---- prologue: stage W1 chunk 0 ----
  {
    const unsigned short* src = w1p;
    #pragma unroll
    for (int i=0;i<4;++i)
      *(short8*)&wbuf[0][tid*8 + i*2048] = *(const short8*)(src + tid*8 + i*2048);
  }

  const int gA = R0 + w*16 + l16;

  // ---- preload A fragments ----
  short8 af[12];
  if (GATHER){
    const unsigned short* p0 = s0 + (size_t)rowI[gA]*Hh + q*8;
    const unsigned short* p1 = s1 + (size_t)colI[gA]*Hh + q*8;
    const float*          p2 = s2f + (size_t)gA*Hh + q*8;
    #pragma unroll
    for (int c=0;c<4;++c){
      af[c]   = *(const short8*)(p0 + c*32);
      af[4+c] = *(const short8*)(p1 + c*32);
      float4 u0 = *(const float4*)(p2 + c*32);
      float4 u1 = *(const float4*)(p2 + c*32 + 4);
      short8 t8;
      t8[0]=(short)f2bf(u0.x); t8[1]=(short)f2bf(u0.y);
      t8[2]=(short)f2bf(u0.z); t8[3]=(short)f2bf(u0.w);
      t8[4]=(short)f2bf(u1.x); t8[5]=(short)f2bf(u1.y);
      t8[6]=(short)f2bf(u1.z); t8[7]=(short)f2bf(u1.w);
      af[8+c] = t8;
    }
  } else {
    int gg = gA < M ? gA : (M-1);
    const unsigned short* p0 = s0 + (size_t)gg*Hh + q*8;
    const unsigned short* p1 = s1 + (size_t)gg*Hh + q*8;
    const unsigned short* p2 = s2b + (size_t)gg*Hh + q*8;
    #pragma unroll
    for (int c=0;c<4;++c){
      af[c]   = *(const short8*)(p0 + c*32);
      af[4+c] = *(const short8*)(p1 + c*32);
      af[8+c] = *(const short8*)(p2 + c*32);
    }
  }

  __syncthreads();   // lds_par + wbuf[0] ready

  const floatx4 fz = {0.f,0.f,0.f,0.f};
  floatx4 acc1[16];
  #pragma unroll
  for (int t=0;t<16;++t) acc1[t] = fz;

  // ---- GEMM1: 12 chunks; W1 double-buffered; c=11 prefetches W2 chunk 0 ----
  #pragma unroll
  for (int c=0;c<12;++c){
    const int sel = c&1, nsel = (c+1)&1;
    short8 nx0, nx1, nx2, nx3;
    if (c < 11){
      const unsigned short* src = w1p + (size_t)(c+1)*8192;
      nx0 = *(const short8*)(src + tid*8);
      nx1 = *(const short8*)(src + tid*8 + 2048);
      nx2 = *(const short8*)(src + tid*8 + 4096);
      nx3 = *(const short8*)(src + tid*8 + 6144);
    } else {
      const unsigned short* src = w2p;
      nx0 = *(const short8*)(src + tid*8);
      nx1 = *(const short8*)(src + tid*8 + 2048);
    }
    #pragma unroll
    for (int t=0;t<16;++t){
      short8 bf = *(const short8*)&wbuf[sel][t*512 + lane*8];
      acc1[t] = __builtin_amdgcn_mfma_f32_16x16x32_bf16(af[c], bf, acc1[t], 0,0,0);
    }
    if (c < 11){
      *(short8*)&wbuf[nsel][tid*8]        = nx0;
      *(short8*)&wbuf[nsel][tid*8 + 2048] = nx1;
      *(short8*)&wbuf[nsel][tid*8 + 4096] = nx2;
      *(short8*)&wbuf[nsel][tid*8 + 6144] = nx3;
    } else {                          // c=11: sel=1, W2 c0 -> wbuf[0]
      *(short8*)&wbuf[0][tid*8]        = nx0;
      *(short8*)&wbuf[0][tid*8 + 2048] = nx1;
    }
    __syncthreads();
  }

  // ---- epilogue 1: bias + LN(256) + GELU -> lds_h (per-wave, no barrier) ----
  #pragma unroll
  for (int r=0;r<4;++r){
    float hv[16];
    float s=0.f, ss=0.f;
    #pragma unroll
    for (int t=0;t<16;++t){
      float v = acc1[t][r] + lds_par[t*16+l16];
      hv[t]=v; s+=v; ss+=v*v;
    }
    #pragma unroll
    for (int m=1;m<16;m<<=1){ s += __shfl_xor(s,m); ss += __shfl_xor(ss,m); }
    float mean = s*(1.f/256.f);
    float var  = ss*(1.f/256.f) - mean*mean;
    float rstd = rsqrtf(var + 1e-5f);
    int ro = q*4 + r;
    #pragma unroll
    for (int t=0;t<16;++t){
      int col = t*16+l16;
      float hh = (hv[t]-mean)*rstd*lds_par[256+col] + lds_par[512+col];
      lds_h[w][ro*264 + col] = f2bf(gelu_f(hh));
    }
  }

  floatx4 acc2[8];
  #pragma unroll
  for (int t=0;t<8;++t) acc2[t] = fz;

  // ---- GEMM2: 8 chunks; W2 double-buffered in LDS (r5-proven) ----
  #pragma unroll
  for (int c=0;c<8;++c){
    const int sel = c&1, nsel = sel^1;
    short8 nx0, nx1;
    if (c < 7){
      const unsigned short* src = w2p + (size_t)(c+1)*4096;
      nx0 = *(const short8*)(src + tid*8);
      nx1 = *(const short8*)(src + tid*8 + 2048);
    }
    short8 a2 = *(const short8*)&lds_h[w][l16*264 + c*32 + q*8];
    #pragma unroll
    for (int t=0;t<8;++t){
      short8 bf = *(const short8*)&wbuf[sel][t*512 + lane*8];
      acc2[t] = __builtin_amdgcn_mfma_f32_16x16x32_bf16(a2, bf, acc2[t], 0,0,0);
    }
    if (c < 7){
      *(short8*)&wbuf[nsel][tid*8]        = nx0;
      *(short8*)&wbuf[nsel][tid*8 + 2048] = nx1;
    }
    __syncthreads();
  }

  // ---- epilogue 2: bias + LN(128) + residual (+ bf16 mirror) ----
  #pragma unroll
  for (int r=0;r<4;++r){
    float vv[8];
    float s=0.f, ss=0.f;
    #pragma unroll
    for (int t=0;t<8;++t){
      float v = acc2[t][r] + lds_par[768 + t*16+l16];
      vv[t]=v; s+=v; ss+=v*v;
    }
    #pragma unroll
    for (int m=1;m<16;m<<=1){ s += __shfl_xor(s,m); ss += __shfl_xor(ss,m); }
    float mean = s*(1.f/128.f);
    float var  = ss*(1.f/128.f) - mean*mean;
    float rstd = rsqrtf(var + 1e-5f);
    int g = R0 + w*16 + q*4 + r;
    if (g < M){
      #pragma unroll
      for (int t=0;t<8;++t){
        int col = t*16+l16;
        float outv = (vv[t]-mean)*rstd*lds_par[896+col] + lds_par[1024+col];
        size_t idx = (size_t)g*Hh + col;
        float nv = resf[idx] + outv;
        resf[idx] = nv;
        if (!GATHER) resb[idx] = f2bf(nv);
      }
    }
  }
}

// ---------------------------------------------------------------------------
// Projection body (device fn): out[M,NCOLS] = bf16(A @ Wp + bias), K=128.
// ---------------------------------------------------------------------------
template<int NCOLS>
__device__ __forceinline__ void proj_body(int bid,
               const unsigned short* __restrict__ A,
               const unsigned short* __restrict__ Wp,
               const float* __restrict__ bias,
               unsigned short* __restrict__ out,
               int M)
{
  constexpr int NT = NCOLS/16;
  const int tid = threadIdx.x;
  const int w = tid>>6, lane = tid&63, l16 = lane&15, q = lane>>4;
  const int R0 = bid*64;
  int gA = R0 + w*16 + l16;
  int ga = gA < M ? gA : (M-1);
  const unsigned short* ap = A + (size_t)ga*128 + q*8;

  const floatx4 fz = {0.f,0.f,0.f,0.f};
  floatx4 acc[NT];
  #pragma unroll
  for (int t=0;t<NT;++t) acc[t] = fz;

  const unsigned short* wl = Wp + (size_t)lane*8;
  #pragma unroll
  for (int c=0;c<4;++c){
    short8 af = *(const short8*)(ap + c*32);
    #pragma unroll
    for (int t=0;t<NT;++t){
      short8 bf = *(const short8*)(wl + (size_t)(c*NT+t)*512);
      acc[t] = __builtin_amdgcn_mfma_f32_16x16x32_bf16(af, bf, acc[t], 0,0,0);
    }
  }
  #pragma unroll
  for (int r=0;r<4;++r){
    int g = R0 + w*16 + q*4 + r;
    if (g < M){
      #pragma unroll
      for (int t=0;t<NT;++t){
        int col = t*16+l16;
        out[(size_t)g*NCOLS + col] = f2bf(acc[t][r] + bias[col]);
      }
    }
  }
}

// ---------------------------------------------------------------------------
// mega_edge: edge MLP (3125, FIRST -- the long pole starts at t=0) then
// kv-proj (313) + qn-proj (313) filling the tail. Disjoint outputs.
// ---------------------------------------------------------------------------
__global__ __launch_bounds__(256, 2)
void mega_edge(const unsigned short* __restrict__ xb,
               const float* __restrict__ ef,
               const int* __restrict__ rowI, const int* __restrict__ colI,
               const unsigned short* __restrict__ w1p,
               const unsigned short* __restrict__ w2p,
               const float* __restrict__ pb1, const float* __restrict__ pg1,
               const float* __restrict__ pbb1,
               const float* __restrict__ pb2, const float* __restrict__ pg2,
               const float* __restrict__ pbb2,
               float* __restrict__ resf,
               const unsigned short* __restrict__ kvp, const float* __restrict__ bkv,
               unsigned short* __restrict__ kvb,
               const unsigned short* __restrict__ qnp, const float* __restrict__ bqn,
               unsigned short* __restrict__ qnb)
{
  int bid = blockIdx.x;
  if (bid < NB_EDGE){
    mlp_body<true>(bid, xb, xb, nullptr, ef, rowI, colI,
                   w1p, w2p, pb1, pg1, pbb1, pb2, pg2, pbb2,
                   resf, nullptr, Ee);
    return;
  }
  bid -= NB_EDGE;
  if (bid < NB_PROJ){
    proj_body<256>(bid, xb, kvp, bkv, kvb, Nn);
    return;
  }
  proj_body<128>(bid - NB_PROJ, xb, qnp, bqn, qnb, Nn);
}

// node MLP (separate dispatch: depends on agg_b/ctx_b)
__global__ __launch_bounds__(256, 2)
void node_mlp(const unsigned short* __restrict__ xb,
              const unsigned short* __restrict__ aggb,
              const unsigned short* __restrict__ ctxb,
              const unsigned short* __restrict__ w1p,
              const unsigned short* __restrict__ w2p,
              const float* __restrict__ pb1, const float* __restrict__ pg1,
              const float* __restrict__ pbb1,
              const float* __restrict__ pb2, const float* __restrict__ pg2,
              const float* __restrict__ pbb2,
              float* __restrict__ resf,
              unsigned short* __restrict__ resb)
{
  mlp_body<false>(blockIdx.x, xb, aggb, ctxb, nullptr, nullptr, nullptr,
                  w1p, w2p, pb1, pg1, pbb1, pb2, pg2, pbb2,
                  resf, resb, Nn);
}

// ---------------------------------------------------------------------------
// mega2: CSR scatter-mean gather (5000 blocks) + token-attn reduce (79).
// ---------------------------------------------------------------------------
__global__ __launch_bounds__(256, 4)
void mega2(const float* __restrict__ ef, const int* __restrict__ rowPtr,
           const int* __restrict__ elist, const float* __restrict__ invd,
           unsigned short* __restrict__ aggb,
           const unsigned short* __restrict__ kv, const float* __restrict__ tq,
           float* __restrict__ onum, float* __restrict__ denom)
{
  const int bid = blockIdx.x;
  const int tid = threadIdx.x;

  if (bid < NB_AGG){
    int n = bid*4 + (tid>>6);
    int lane = tid&63;
    if (n >= Nn) return;
    int j0 = rowPtr[n], j1 = rowPtr[n+1];
    float s0=0.f,s1=0.f,t0=0.f,t1=0.f,u0=0.f,u1=0.f,v0=0.f,v1=0.f;
    int j = j0;
    for (; j+3 < j1; j += 4){
      int e0=elist[j], e1=elist[j+1], e2=elist[j+2], e3=elist[j+3];
      float2 a = *(const float2*)(ef + (size_t)e0*Hh + lane*2);
      float2 b = *(const float2*)(ef + (size_t)e1*Hh + lane*2);
      float2 c = *(const float2*)(ef + (size_t)e2*Hh + lane*2);
      float2 d = *(const float2*)(ef + (size_t)e3*Hh + lane*2);
      s0+=a.x; s1+=a.y; t0+=b.x; t1+=b.y; u0+=c.x; u1+=c.y; v0+=d.x; v1+=d.y;
    }
    for (; j < j1; ++j){
      int e0 = elist[j];
      float2 a = *(const float2*)(ef + (size_t)e0*Hh + lane*2);
      s0+=a.x; s1+=a.y;
    }
    s0 += t0+u0+v0; s1 += t1+u1+v1;
    float iv = invd[n];
    unsigned int packed = ((unsigned)f2bf(s1*iv) << 16) | (unsigned)f2bf(s0*iv);
    *(unsigned int*)&aggb[(size_t)n*Hh + lane*2] = packed;
    return;
  }

  // ---- token-attention reduce ----
  __shared__ float sbuf[8][256];
  __shared__ float qs[256];
  qs[tid] = tq[tid];
  __syncthreads();
  const int base = (bid - NB_AGG)*256;
  const int i = base + tid;
  float ex[8];
  if (i < Nn){
    const unsigned short* kr = kv + (size_t)i*256;
    float acc[8];
    #pragma unroll
    for (int a=0;a<8;++a) acc[a]=0.f;
    #pragma unroll
    for (int d8=0; d8<16; ++d8){
      short8 k8 = *(const short8*)(kr + d8*8);
      #pragma unroll
      for (int u=0;u<8;++u){
        int d = d8*8+u;
        float kd = bf2f((unsigned short)k8[u]);
        int h = d>>5;
        acc[h]   += qs[d]*kd;
        acc[4+h] += qs[128+d]*kd;
      }
    }
    #pragma unroll
    for (int a=0;a<8;++a) ex[a] = expf(acc[a]*0.17677669529663688f);
  } else {
    #pragma unroll
    for (int a=0;a<8;++a) ex[a]=0.f;
  }
  #pragma unroll
  for (int a=0;a<8;++a) sbuf[a][tid] = ex[a];
  __syncthreads();

  const int jh = tid>>7, h = (tid>>5)&3, d = tid&31;
  int cnt = Nn - base; if (cnt > 256) cnt = 256;
  int j0 = jh*128, j1 = j0+128;
  if (j0 > cnt) j0 = cnt;
  if (j1 > cnt) j1 = cnt;
  float a0=0.f, a1=0.f, w0s=0.f, w1s=0.f;
  for (int j=j0; j<j1; ++j){
    float w0 = sbuf[h][j];
    float w1 = sbuf[4+h][j];
    float vv = bf2f(kv[(size_t)(base+j)*256 + 128 + h*32 + d]);
    a0 += w0*vv; a1 += w1*vv; w0s += w0; w1s += w1;
  }
  atomicAdd(&onum[h*32+d], a0);
  atomicAdd(&onum[128+h*32+d], a1);
  if (d==0){ atomicAdd(&denom[h], w0s); atomicAdd(&denom[4+h], w1s); }
}

// ---------------------------------------------------------------------------
// Token transformer block (2 tokens, fp32) + node-attn k/v projection.
// ---------------------------------------------------------------------------
__global__ void token_kernel(const float* __restrict__ onum, const float* __restrict__ denom,
  const float* __restrict__ tok_wo, const float* __restrict__ tok_bo,
  const float* __restrict__ token_embed,
  const float* __restrict__ g1, const float* __restrict__ b1,
  const float* __restrict__ g2, const float* __restrict__ b2,
  const float* __restrict__ ff_w1, const float* __restrict__ ff_b1,
  const float* __restrict__ ff_w2, const float* __restrict__ ff_b2,
  const float* __restrict__ nod_wqkv, const float* __restrict__ nod_bqkv,
  float* __restrict__ kv2)
{
  __shared__ float O[2][128];
  __shared__ float T[2][128];
  __shared__ float F[2][512];
  __shared__ float stats[4];
  int tid = threadIdx.x;
  int t = tid>>7, c = tid&127;
  {
    int th = t*4 + (c>>5);
    O[t][c] = onum[th*32 + (c&31)] / denom[th];
  }
  __syncthreads();
  {
    float s = tok_bo[c];
    for (int k=0;k<128;++k) s += O[t][k]*tok_wo[k*128+c];
    T[t][c] = token_embed[t*128+c] + s;
  }
  __syncthreads();
  if (tid < 2){
    float s=0.f, ss=0.f;
    for (int k=0;k<128;++k){ float v=T[tid][k]; s+=v; ss+=v*v; }
    float m = s*(1.f/128.f);
    stats[tid*2] = m;
    stats[tid*2+1] = rsqrtf(ss*(1.f/128.f)-m*m+1e-5f);
  }
  __syncthreads();
  T[t][c] = (T[t][c]-stats[t*2])*stats[t*2+1]*g1[c] + b1[c];
  __syncthreads();
  for (int u=0;u<4;++u){
    int o = tid + u*256;
    int tt = o>>9, j = o&511;
    float s = ff_b1[j];
    for (int k=0;k<128;++k) s += T[tt][k]*ff_w1[k*512+j];
    F[tt][j] = gelu_f(s);
  }
  __syncthreads();
  {
    float s = ff_b2[c];
    for (int k=0;k<512;++k) s += F[t][k]*ff_w2[k*128+c];
    O[t][c] = T[t][c] + s;
  }
  __syncthreads();
  if (tid < 2){
    float s=0.f, ss=0.f;
    for (int k=0;k<128;++k){ float v=O[tid][k]; s+=v; ss+=v*v; }
    float m = s*(1.f/128.f);
    stats[tid*2] = m;
    stats[tid*2+1] = rsqrtf(ss*(1.f/128.f)-m*m+1e-5f);
  }
  __syncthreads();
  O[t][c] = (O[t][c]-stats[t*2])*stats[t*2+1]*g2[c] + b2[c];
  __syncthreads();
  for (int u=0;u<2;++u){
    int o = tid + u*256;
    int tt = o>>8, cc = o&255;
    float s = nod_bqkv[128+cc];
    for (int k=0;k<128;++k) s += O[tt][k]*nod_wqkv[k*384+128+cc];
    if (cc < 128) kv2[tt*128+cc] = s;                  // k2
    else          kv2[256 + tt*128 + (cc-128)] = s;    // v2
  }
}

// ---------------------------------------------------------------------------
// attn_wo_gemm: per-node attention over the 2 global tokens computed
// in-register as the A-fragment of the wo GEMM.
// ---------------------------------------------------------------------------
__global__ __launch_bounds__(256, 4)
void attn_wo_gemm(const unsigned short* __restrict__ qn,
                  const float* __restrict__ kv2,
                  const unsigned short* __restrict__ wop,
                  const float* __restrict__ nod_bo,
                  unsigned short* __restrict__ out,
                  int M)
{
  __shared__ float k2s[256], v2s[256];
  const int tid = threadIdx.x;
  k2s[tid] = kv2[tid];
  v2s[tid] = kv2[256+tid];
  __syncthreads();
  const int w = tid>>6, lane = tid&63, l16 = lane&15, q = lane>>4;
  const int R0 = blockIdx.x*64;
  int gA = R0 + w*16 + l16;
  int ga = gA < M ? gA : (M-1);
  const unsigned short* ap = qn + (size_t)ga*128 + q*8;

  const floatx4 fz = {0.f,0.f,0.f,0.f};
  floatx4 acc[8];
  #pragma unroll
  for (int t=0;t<8;++t) acc[t] = fz;
  const unsigned short* wl = wop + (size_t)lane*8;

  #pragma unroll
  for (int c=0;c<4;++c){
    short8 qv8 = *(const short8*)(ap + c*32);
    float qv[8];
    float p0=0.f, p1=0.f;
    #pragma unroll
    for (int j=0;j<8;++j){
      qv[j] = bf2f((unsigned short)qv8[j]);
      int col = c*32 + q*8 + j;          // head = c for all 8 cols
      p0 += qv[j]*k2s[col];
      p1 += qv[j]*k2s[128+col];
    }
    p0 += __shfl_xor(p0,16); p0 += __shfl_xor(p0,32);  // reduce over q
    p1 += __shfl_xor(p1,16); p1 += __shfl_xor(p1,32);
    float e0 = __expf(p0*0.17677669529663688f);
    float e1 = __expf(p1*0.17677669529663688f);
    float inv = 1.0f/(e0+e1);
    short8 a;
    #pragma unroll
    for (int j=0;j<8;++j){
      int col = c*32 + q*8 + j;
      a[j] = (short)f2bf((e0*v2s[col] + e1*v2s[128+col])*inv);
    }
    #pragma unroll
    for (int t=0;t<8;++t){
      short8 bf = *(const short8*)(wl + (size_t)(c*8+t)*512);
      acc[t] = __builtin_amdgcn_mfma_f32_16x16x32_bf16(a, bf, acc[t], 0,0,0);
    }
  }
  #pragma unroll
  for (int r=0;r<4;++r){
    int g = R0 + w*16 + q*4 + r;
    if (g < M){
      #pragma unroll
      for (int t=0;t<8;++t){
        int col = t*16+l16;
        out[(size_t)g*128 + col] = f2bf(acc[t][r] + nod_bo[col]);
      }
    }
  }
}

// ---------------------------------------------------------------------------
// CSR build (one-time; edge_index constant across layers).
// ---------------------------------------------------------------------------
__global__ void csr_prefix(const int* __restrict__ cnt, int* __restrict__ rowPtr)
{
  __shared__ int part[256];
  const int tid = threadIdx.x;
  const int CH = (Nn + 255)/256;
  int c0 = tid*CH; if (c0 > Nn) c0 = Nn;
  int c1 = c0+CH;  if (c1 > Nn) c1 = Nn;
  int s = 0;
  for (int i=c0;i<c1;++i) s += cnt[i];
  part[tid] = s;
  __syncthreads();
  for (int d=1; d<256; d<<=1){
    int v = (tid>=d) ? part[tid-d] : 0;
    __syncthreads();
    part[tid] += v;
    __syncthreads();
  }
  int off = part[tid] - s;
  for (int i=c0;i<c1;++i){ rowPtr[i] = off; off += cnt[i]; }
  if (tid == 255) rowPtr[Nn] = off;
}

__global__ void csr_fill(const int* __restrict__ colI, const int* __restrict__ rowPtr,
                         int* __restrict__ cursor, int* __restrict__ elist)
{
  int e = blockIdx.x*256 + threadIdx.x;
  if (e < Ee){
    int n = colI[e];
    int p = atomicAdd(&cursor[n], 1);
    elist[rowPtr[n] + p] = e;
  }
}

// ---------------------------------------------------------------------------
// One-time prep: fp32 -> bf16 weight packing into MFMA fragment order.
// ---------------------------------------------------------------------------
__global__ void prep_weights(const float* __restrict__ ew1,
  const float* __restrict__ ew2,
  const float* __restrict__ nw1,
  const float* __restrict__ nw2,
  const float* __restrict__ tok_wqkv,
  const float* __restrict__ nod_wqkv,
  const float* __restrict__ nod_wo,
  const float* __restrict__ token_embed,
  const float* __restrict__ tok_bqkv,
  unsigned short* __restrict__ ew1p, unsigned short* __restrict__ ew2p,
  unsigned short* __restrict__ nw1p, unsigned short* __restrict__ nw2p,
  unsigned short* __restrict__ kvp, unsigned short* __restrict__ qnp,
  unsigned short* __restrict__ wop, float* __restrict__ tq)
{
  int gid = blockIdx.x*256 + threadIdx.x;
  if (gid < Ll*98304){             // W1 pack: [12 chunks][16 tiles][64 lanes][8]
    int l = gid / 98304; int idx = gid % 98304;
    int c = idx >> 13;
    int t = (idx >> 9) & 15;
    int lane = (idx >> 3) & 63;
    int j = idx & 7;
    int k = c*32 + (lane>>4)*8 + j;
    int n = t*16 + (lane&15);
    size_t src = (size_t)l*98304 + (size_t)k*256 + n;
    ew1p[gid] = f2bf(ew1[src]);
    nw1p[gid] = f2bf(nw1[src]);
  }
  if (gid < Ll*32768){             // W2 pack: [8 chunks][8 tiles][64][8]
    int l = gid / 32768; int idx = gid % 32768;
    int c = idx >> 12;
    int t = (idx >> 9) & 7;
    int lane = (idx >> 3) & 63;
    int j = idx & 7;
    int k = c*32 + (lane>>4)*8 + j;
    int n = t*16 + (lane&15);
    size_t src = (size_t)l*32768 + (size_t)k*128 + n;
    ew2p[gid] = f2bf(ew2[src]);
    nw2p[gid] = f2bf(nw2[src]);
  }
  if (gid < 32768){                // kv proj pack: [4 chunks][16 tiles][64][8]
    int c = gid >> 13;
    int t = (gid >> 9) & 15;
    int lane = (gid >> 3) & 63;
    int j = gid & 7;
    int k = c*32 + (lane>>4)*8 + j;
    int n = t*16 + (lane&15);
    kvp[gid] = f2bf(tok_wqkv[(size_t)k*384 + 128 + n]);
  }
  if (gid < 16384){                // q / wo pack: [4 chunks][8 tiles][64][8]
    int c = gid >> 12;
    int t = (gid >> 9) & 7;
    int lane = (gid >> 3) & 63;
    int j = gid & 7;
    int k = c*32 + (lane>>4)*8 + j;
    int n = t*16 + (lane&15);
    qnp[gid] = f2bf(nod_wqkv[(size_t)k*384 + n]);
    wop[gid] = f2bf(nod_wo[(size_t)k*128 + n]);
  }
  if (gid < 256){
    int t = gid >> 7, c = gid & 127;
    float s = tok_bqkv[c];
    for (int k=0;k<128;++k) s += token_embed[t*128+k] * tok_wqkv[k*384+c];
    tq[gid] = s;
  }
}

__global__ void init_state(const float* __restrict__ x_in,
  const float* __restrict__ e_in,
  float* __restrict__ x_f32, float* __restrict__ e_f32,
  unsigned short* __restrict__ x_b16)
{
  size_t gid = (size_t)blockIdx.x*256 + threadIdx.x;
  if (gid < (size_t)Ee*Hh) e_f32[gid] = e_in[gid];
  if (gid < (size_t)Nn*Hh){
    float v = x_in[gid];
    x_f32[gid] = v;
    x_b16[gid] = f2bf(v);
  }
}

__global__ void deg_count(const int* __restrict__ colI, int* __restrict__ cnt){
  int gid = blockIdx.x*256+threadIdx.x;
  if (gid < Ee) atomicAdd(&cnt[colI[gid]], 1);
}
__global__ void deg_inv(const int* __restrict__ cnt, float* __restrict__ inv){
  int gid = blockIdx.x*256+threadIdx.x;
  if (gid < Nn){ int c = cnt[gid]; inv[gid] = 1.0f / (float)(c > 1 ? c : 1); }
}

// ---------------------------------------------------------------------------
extern "C" void kernel_launch(void* const* d_in, const int* in_sizes, int n_in,
                              void* d_out, int out_size, void* d_ws, size_t ws_size,
                              hipStream_t stream)
{
  const float* x_in       = (const float*)d_in[0];
  const int*   eidx       = (const int*)d_in[1];
  const float* e_in       = (const float*)d_in[2];
  const float* edge_w1    = (const float*)d_in[3];
  const float* edge_b1    = (const float*)d_in[4];
  const float* edge_ln1g  = (const float*)d_in[5];
  const float* edge_ln1b  = (const float*)d_in[6];
  const float* edge_w2    = (const float*)d_in[7];
  const float* edge_b2    = (const float*)d_in[8];
  const float* edge_ln2g  = (const float*)d_in[9];
  const float* edge_ln2b  = (const float*)d_in[10];
  const float* node_w1    = (const float*)d_in[11];
  const float* node_b1    = (const float*)d_in[12];
  const float* node_ln1g  = (const float*)d_in[13];
  const float* node_ln1b  = (const float*)d_in[14];
  const float* node_w2    = (const float*)d_in[15];
  const float* node_b2    = (const float*)d_in[16];
  const float* node_ln2g  = (const float*)d_in[17];
  const float* node_ln2b  = (const float*)d_in[18];
  const float* token_embed= (const float*)d_in[19];
  const float* tok_wqkv   = (const float*)d_in[20];
  const float* tok_bqkv   = (const float*)d_in[21];
  const float* tok_wo     = (const float*)d_in[22];
  const float* tok_bo     = (const float*)d_in[23];
  const float* ln_t1g     = (const float*)d_in[24];
  const float* ln_t1b     = (const float*)d_in[25];
  const float* ln_t2g     = (const float*)d_in[26];
  const float* ln_t2b     = (const float*)d_in[27];
  const float* ff_w1      = (const float*)d_in[28];
  const float* ff_b1      = (const float*)d_in[29];
  const float* ff_w2      = (const float*)d_in[30];
  const float* ff_b2      = (const float*)d_in[31];
  const float* nod_wqkv   = (const float*)d_in[32];
  const float* nod_bqkv   = (const float*)d_in[33];
  const float* nod_wo     = (const float*)d_in[34];
  const float* nod_bo     = (const float*)d_in[35];

  const int* rowI = eidx;
  const int* colI = eidx + Ee;

  float* out_x = (float*)d_out;                    // fp32 master of x (output 0)
  float* out_e = out_x + (size_t)Nn*Hh;            // fp32 master of edge_attr (output 1)

  char* base = (char*)d_ws;
  size_t off = 0;
  auto alloc = [&](size_t bytes)->char*{
    char* p = base + off; off += (bytes + 255) & ~(size_t)255; return p;
  };
  unsigned short* x_b16 = (unsigned short*)alloc((size_t)Nn*Hh*2);
  unsigned short* agg_b = (unsigned short*)alloc((size_t)Nn*Hh*2);
  unsigned short* ctx_b = (unsigned short*)alloc((size_t)Nn*Hh*2);
  unsigned short* kv_b  = (unsigned short*)alloc((size_t)Nn*256*2);
  unsigned short* qn_b  = (unsigned short*)alloc((size_t)Nn*Hh*2);
  float*          invd  = (float*)alloc((size_t)Nn*4);
  int*            dcnt  = (int*)alloc((size_t)Nn*4);
  int*            rowP  = (int*)alloc((size_t)(Nn+1)*4);
  int*            curs  = (int*)alloc((size_t)Nn*4);
  int*            elist = (int*)alloc((size_t)Ee*4);
  unsigned short* ew1p  = (unsigned short*)alloc((size_t)Ll*98304*2);
  unsigned short* ew2p  = (unsigned short*)alloc((size_t)Ll*32768*2);
  unsigned short* nw1p  = (unsigned short*)alloc((size_t)Ll*98304*2);
  unsigned short* nw2p  = (unsigned short*)alloc((size_t)Ll*32768*2);
  unsigned short* kvp   = (unsigned short*)alloc((size_t)32768*2);
  unsigned short* qnp   = (unsigned short*)alloc((size_t)16384*2);
  unsigned short* wop   = (unsigned short*)alloc((size_t)16384*2);
  float*          tq    = (float*)alloc(256*4);
  float*          kv2   = (float*)alloc(512*4);
  float*          onum  = (float*)alloc(264*4);
  float*          denom = onum + 256;
  if (off > ws_size) return;  // insufficient workspace: fail loudly (no writes)

  hipMemsetAsync(dcnt, 0, (size_t)Nn*4, stream);
  hipMemsetAsync(curs, 0, (size_t)Nn*4, stream);
  prep_weights<<<(Ll*98304 + 255)/256, 256, 0, stream>>>(
      edge_w1, edge_w2, node_w1, node_w2, tok_wqkv, nod_wqkv, nod_wo,
      token_embed, tok_bqkv, ew1p, ew2p, nw1p, nw2p, kvp, qnp, wop, tq);
  init_state<<<(int)(((size_t)Ee*Hh + 255)/256), 256, 0, stream>>>(
      x_in, e_in, out_x, out_e, x_b16);
  deg_count<<<(Ee+255)/256, 256, 0, stream>>>(colI, dcnt);
  csr_prefix<<<1, 256, 0, stream>>>(dcnt, rowP);
  deg_inv<<<(Nn+255)/256, 256, 0, stream>>>(dcnt, invd);
  csr_fill<<<(Ee+255)/256, 256, 0, stream>>>(colI, rowP, curs, elist);

  for (int l = 0; l < Ll; ++l){
    hipMemsetAsync(onum, 0, 264*4, stream);

    // edge MLP (first) + kv/qn projections (tail fill), one dispatch
    mega_edge<<<NB_EDGE + 2*NB_PROJ, 256, 0, stream>>>(
        x_b16, out_e, rowI, colI,
        ew1p + (size_t)l*98304, ew2p + (size_t)l*32768,
        edge_b1 + l*256, edge_ln1g + l*256, edge_ln1b + l*256,
        edge_b2 + l*128, edge_ln2g + l*128, edge_ln2b + l*128,
        out_e,
        kvp, tok_bqkv+128, kv_b,
        qnp, nod_bqkv, qn_b);

    // scatter-mean gather + token-attn reduce (one dispatch)
    mega2<<<NB_AGG + NB_ATTN, 256, 0, stream>>>(
        out_e, rowP, elist, invd, agg_b, kv_b, tq, onum, denom);

    token_kernel<<<1, 256, 0, stream>>>(onum, denom, tok_wo, tok_bo, token_embed,
        ln_t1g, ln_t1b, ln_t2g, ln_t2b, ff_w1, ff_b1, ff_w2, ff_b2,
        nod_wqkv, nod_bqkv, kv2);

    // fused per-node attention + wo projection
    attn_wo_gemm<<<NB_PROJ, 256, 0, stream>>>(qn_b, kv2, wop, nod_bo, ctx_b, Nn);

    // node MLP + residual (refreshes x bf16 mirror)
    node_mlp<<<NB_PROJ, 256, 0, stream>>>(x_b16, agg_b, ctx_b,
        nw1p + (size_t)l*98304, nw2p + (size_t)l*32768,
        node_b1 + l*256, node_ln1g + l*256, node_ln1b + l*256,
        node_b2 + l*128, node_ln2g + l*128, node_ln2b + l*128,
        out_x, x_b16);
  }
}